// Round 4
// baseline (5276.303 us; speedup 1.0000x reference)
//
#include <hip/hip_runtime.h>

// PointNet++ SetAbstraction: FPS -> ball query -> grouped MLP(67->64->64->128, BN+ReLU) -> maxpool
// B=8, N=8192, S=2048, K=32, F=64.
//
// d_in order: 0 xyzs, 1 feats, then per layer i=1..3: w,b,g,bt,m,v.
// d_out: [8][2048][3] center_xyzs followed by [8][2048][128] center_feats (fp32).
// d_ws: 16576 floats (66.3 KB) of transposed weights.
//
// EXACTNESS: FPS argmax and ball-query membership are discrete decisions; a
// 1-ulp difference flips them and cascades. Discrete-decision math lives in
// helpers with `#pragma clang fp contract(off)`. Association evidence so far:
//   - np.sum over last axis (n=3): FORWARD plain adds (x0+x1)+x2 — PASSES
//     (FPS / |c|^2 / |x|^2: squares materialized then reduced, no FMA).
//   - ball-query dot: forward mul/add FAILED and descending mul/add FAILED
//     with IDENTICAL absmax 0.6875 -> reference keeps product precision ->
//     FMA chain (XLA CPU dot emitter / Eigen, k ascending):
//     dt = fma(c2,x2, fma(c1,x1, c0*x0)).   <- this round
// Continuous MLP path uses fmaf freely (threshold 5.4e-2).

#define NPTS 8192
#define SCTR 2048
#define NB   8
#define KNN  32
#define NF   64

// d = (dx*dx + dy*dy) + dz*dz, exact fp32 mul/add order, NO contraction.
__device__ __forceinline__ float fps_sqdist(float ax, float ay, float az,
                                            float bx, float by, float bz) {
#pragma clang fp contract(off)
  float dx = ax - bx;
  float dy = ay - by;
  float dz = az - bz;
  return (dx * dx + dy * dy) + dz * dz;
}

// (x*x + y*y) + z*z, NO contraction (np.sum forward order, n=3).
__device__ __forceinline__ float sumsq3(float x, float y, float z) {
#pragma clang fp contract(off)
  return (x * x + y * y) + z * z;
}

// Ball-query expanded form: (sc + sx) - 2*dot, NO contraction on the adds.
// dot = ascending-k FMA chain: fma(cz,z, fma(cy,y, cx*x)).
__device__ __forceinline__ float bq_d2(float sc, float sx,
                                       float cx, float cy, float cz,
                                       float x, float y, float z) {
#pragma clang fp contract(off)
  float dt = fmaf(cz, z, fmaf(cy, y, cx * x));
  return (sc + sx) - 2.0f * dt;
}

// ---------------------------------------------------------------------------
// Kernel 1: blocks 0..7 = FPS (one block per batch), blocks 8..24 = weight
// transpose into workspace (w1T[67][64], w2T[64][64], w3T[64][128]).
// ---------------------------------------------------------------------------
__global__ __launch_bounds__(1024) void fps_transpose_kernel(
    const float* __restrict__ xyzs,
    const float* __restrict__ w1, const float* __restrict__ w2, const float* __restrict__ w3,
    float* __restrict__ centers, float* __restrict__ wT)
{
  const int t = threadIdx.x;
  if (blockIdx.x >= NB) {
    int idx = (blockIdx.x - NB) * 1024 + t;
    if (idx < 67*64) {
      int c = idx >> 6, o = idx & 63;
      wT[idx] = w1[o*67 + c];
    } else if (idx < 67*64 + 64*64) {
      int r = idx - 67*64; int c = r >> 6, o = r & 63;
      wT[idx] = w2[o*64 + c];
    } else if (idx < 67*64 + 64*64 + 64*128) {
      int r = idx - (67*64 + 64*64); int c = r >> 7, o = r & 127;
      wT[idx] = w3[o*64 + c];
    }
    return;
  }

  const int b = blockIdx.x;
  const float* xb = xyzs + (size_t)b * NPTS * 3;

  // 8 points per thread, p = t*8 + j (ascending global index within thread).
  float px[8], py[8], pz[8], mind[8];
  {
    const float4* s4 = (const float4*)xb + t * 6;  // 6 float4 = 24 floats = 8 pts
#pragma unroll
    for (int gq = 0; gq < 2; ++gq) {
      float4 v0 = s4[3*gq+0], v1 = s4[3*gq+1], v2 = s4[3*gq+2];
      int j = 4*gq;
      px[j+0]=v0.x; py[j+0]=v0.y; pz[j+0]=v0.z;
      px[j+1]=v0.w; py[j+1]=v1.x; pz[j+1]=v1.y;
      px[j+2]=v1.z; py[j+2]=v1.w; pz[j+2]=v2.x;
      px[j+3]=v2.y; py[j+3]=v2.z; pz[j+3]=v2.w;
    }
#pragma unroll
    for (int j = 0; j < 8; ++j) mind[j] = 1e10f;  // same f32 as ref's 1e10
  }

  __shared__ float redv[2][16];
  __shared__ int   redi[2][16];
  __shared__ int   hist[SCTR];
  if (t == 0) hist[0] = 0;  // reference: first center is index 0

  int cur = 0;
  for (int s = 1; s < SCTR; ++s) {
    // broadcast load of current center coords (same addr all lanes -> 1 txn)
    float lx = xb[cur*3+0], ly = xb[cur*3+1], lz = xb[cur*3+2];

    float bv = -1.0f; int bj = 0;
#pragma unroll
    for (int j = 0; j < 8; ++j) {
      float d = fps_sqdist(px[j], py[j], pz[j], lx, ly, lz);
      float m = fminf(mind[j], d);
      mind[j] = m;
      if (m > bv) { bv = m; bj = j; }   // strict > keeps smallest j (first-index argmax)
    }
    int gi = t * 8 + bj;

    // wave-level argmax reduce with first-index tie-break (associative+commutative)
#pragma unroll
    for (int mm = 1; mm < 64; mm <<= 1) {
      float ov = __shfl_xor(bv, mm);
      int   oi = __shfl_xor(gi, mm);
      if (ov > bv || (ov == bv && oi < gi)) { bv = ov; gi = oi; }
    }

    int pb = s & 1;  // double-buffered cross-wave scratch: one barrier per step
    if ((t & 63) == 0) { int w = t >> 6; redv[pb][w] = bv; redi[pb][w] = gi; }
    __syncthreads();
    float v0 = redv[pb][0]; int i0 = redi[pb][0];
#pragma unroll
    for (int w = 1; w < 16; ++w) {
      float v1 = redv[pb][w]; int i1 = redi[pb][w];
      if (v1 > v0 || (v1 == v0 && i1 < i0)) { v0 = v1; i0 = i1; }
    }
    cur = i0;                     // identical on every thread
    if (t == 0) hist[s] = cur;
  }
  __syncthreads();

  for (int s = t; s < SCTR; s += 1024) {
    int i = hist[s];
    float* o = centers + ((size_t)b * SCTR + s) * 3;
    o[0] = xb[i*3+0]; o[1] = xb[i*3+1]; o[2] = xb[i*3+2];
  }
}

// ---------------------------------------------------------------------------
// Kernel 2: one 64-thread wave per center. Ball query (first K ascending
// index within radius, exact expanded-form d2), gather to LDS, 3-layer MLP
// with per-lane 4k x 8o register tile, BN+ReLU, maxpool over K, store.
// ---------------------------------------------------------------------------
__global__ __launch_bounds__(64) void sa_fused_kernel(
    const float* __restrict__ xyzs, const float* __restrict__ feats,
    const float* centers, const float* __restrict__ wT,
    const float* __restrict__ b1, const float* __restrict__ g1, const float* __restrict__ bt1,
    const float* __restrict__ m1, const float* __restrict__ v1,
    const float* __restrict__ b2, const float* __restrict__ g2, const float* __restrict__ bt2,
    const float* __restrict__ m2, const float* __restrict__ v2,
    const float* __restrict__ b3, const float* __restrict__ g3, const float* __restrict__ bt3,
    const float* __restrict__ m3, const float* __restrict__ v3,
    float* out_feats)
{
  constexpr float R2 = (float)(0.2 * 0.2);  // f32(0.04000000000000001) — matches ref predicate
  const int bid  = blockIdx.x;
  const int b    = bid >> 11;
  const int lane = threadIdx.x;
  const float* xb = xyzs + (size_t)b * NPTS * 3;
  const float* cp = centers + (size_t)bid * 3;
  float cx = cp[0], cy = cp[1], cz = cp[2];
  float sc = sumsq3(cx, cy, cz);

  __shared__ int   gidx[KNN];
  __shared__ float in_[32*67];   // stride 67 (conflict-free for the 4k in-reads)
  __shared__ float y_[32*65];    // stride 65

  // ---- ball query: first 32 in-radius points by ascending index ----
  int cnt = 0;
  for (int base = 0; base < NPTS && cnt < KNN; base += 64) {
    int n = base + lane;
    float x = xb[n*3+0], y = xb[n*3+1], z = xb[n*3+2];
    float sx = sumsq3(x, y, z);
    float d2 = bq_d2(sc, sx, cx, cy, cz, x, y, z);
    bool within = (d2 <= R2);
    unsigned long long mk = __ballot(within);
    int rank = __popcll(mk & ((1ull << lane) - 1ull));
    int slot = cnt + rank;
    if (within && slot < KNN) gidx[slot] = n;
    cnt += (int)__popcll(mk);
  }
  if (cnt > KNN) cnt = KNN;
  __syncthreads();

  // ---- gather: in_[k][0..2] = xyz - center, in_[k][3..66] = feats; zeros if invalid ----
#pragma unroll 4
  for (int k = 0; k < KNN; ++k) {
    int gk = (k < cnt) ? gidx[k] : -1;
    float fv = 0.f, xv = 0.f;
    if (gk >= 0) {
      fv = feats[((size_t)b * NPTS + gk) * NF + lane];
      if (lane < 3) xv = xb[gk*3 + lane] - cp[lane];  // exact single op
    }
    in_[k*67 + 3 + lane] = fv;
    if (lane < 3) in_[k*67 + lane] = xv;
  }
  __syncthreads();

  const int g = lane >> 3;  // k-group: k = 4g..4g+3
  const int h = lane & 7;   // o-group: o = 8h..8h+7
  const float* w1T = wT;                  // [67][64]
  const float* w2T = wT + 67*64;          // [64][64]
  const float* w3T = wT + 67*64 + 64*64;  // [64][128]

  // ---- Layer 1: 67 -> 64 ----
  {
    float acc[4][8];
#pragma unroll
    for (int i=0;i<4;++i)
#pragma unroll
      for (int j=0;j<8;++j) acc[i][j]=0.f;
    for (int c = 0; c < 67; ++c) {
      float a0 = in_[(4*g+0)*67 + c];
      float a1 = in_[(4*g+1)*67 + c];
      float a2 = in_[(4*g+2)*67 + c];
      float a3 = in_[(4*g+3)*67 + c];
      const float* wr = w1T + c*64 + 8*h;
      float4 wv0 = *(const float4*)(wr);
      float4 wv1 = *(const float4*)(wr + 4);
      float wj[8] = {wv0.x,wv0.y,wv0.z,wv0.w,wv1.x,wv1.y,wv1.z,wv1.w};
#pragma unroll
      for (int j=0;j<8;++j) {
        acc[0][j] = fmaf(a0, wj[j], acc[0][j]);
        acc[1][j] = fmaf(a1, wj[j], acc[1][j]);
        acc[2][j] = fmaf(a2, wj[j], acc[2][j]);
        acc[3][j] = fmaf(a3, wj[j], acc[3][j]);
      }
    }
    float scl[8], shf[8];
#pragma unroll
    for (int j=0;j<8;++j) {
      int o = 8*h + j;
      float r = g1[o] * rsqrtf(v1[o] + 1e-5f);
      scl[j] = r;
      shf[j] = (b1[o] - m1[o]) * r + bt1[o];
    }
#pragma unroll
    for (int i=0;i<4;++i) {
      int k = 4*g + i;
#pragma unroll
      for (int j=0;j<8;++j)
        y_[k*65 + 8*h + j] = fmaxf(fmaf(acc[i][j], scl[j], shf[j]), 0.f);
    }
  }
  __syncthreads();

  // ---- Layer 2: 64 -> 64 (reads y_, writes in_ reused at stride 65) ----
  {
    float acc[4][8];
#pragma unroll
    for (int i=0;i<4;++i)
#pragma unroll
      for (int j=0;j<8;++j) acc[i][j]=0.f;
    for (int c = 0; c < 64; ++c) {
      float a0 = y_[(4*g+0)*65 + c];
      float a1 = y_[(4*g+1)*65 + c];
      float a2 = y_[(4*g+2)*65 + c];
      float a3 = y_[(4*g+3)*65 + c];
      const float* wr = w2T + c*64 + 8*h;
      float4 wv0 = *(const float4*)(wr);
      float4 wv1 = *(const float4*)(wr + 4);
      float wj[8] = {wv0.x,wv0.y,wv0.z,wv0.w,wv1.x,wv1.y,wv1.z,wv1.w};
#pragma unroll
      for (int j=0;j<8;++j) {
        acc[0][j] = fmaf(a0, wj[j], acc[0][j]);
        acc[1][j] = fmaf(a1, wj[j], acc[1][j]);
        acc[2][j] = fmaf(a2, wj[j], acc[2][j]);
        acc[3][j] = fmaf(a3, wj[j], acc[3][j]);
      }
    }
    float scl[8], shf[8];
#pragma unroll
    for (int j=0;j<8;++j) {
      int o = 8*h + j;
      float r = g2[o] * rsqrtf(v2[o] + 1e-5f);
      scl[j] = r;
      shf[j] = (b2[o] - m2[o]) * r + bt2[o];
    }
    __syncthreads();  // order old in_ reads before overwrite
#pragma unroll
    for (int i=0;i<4;++i) {
      int k = 4*g + i;
#pragma unroll
      for (int j=0;j<8;++j)
        in_[k*65 + 8*h + j] = fmaxf(fmaf(acc[i][j], scl[j], shf[j]), 0.f);
    }
  }
  __syncthreads();

  // ---- Layer 3: 64 -> 128 in two o-passes, BN+ReLU, maxpool over k, store ----
  for (int p = 0; p < 2; ++p) {
    float acc[4][8];
#pragma unroll
    for (int i=0;i<4;++i)
#pragma unroll
      for (int j=0;j<8;++j) acc[i][j]=0.f;
    for (int c = 0; c < 64; ++c) {
      float a0 = in_[(4*g+0)*65 + c];
      float a1 = in_[(4*g+1)*65 + c];
      float a2 = in_[(4*g+2)*65 + c];
      float a3 = in_[(4*g+3)*65 + c];
      const float* wr = w3T + c*128 + p*64 + 8*h;
      float4 wv0 = *(const float4*)(wr);
      float4 wv1 = *(const float4*)(wr + 4);
      float wj[8] = {wv0.x,wv0.y,wv0.z,wv0.w,wv1.x,wv1.y,wv1.z,wv1.w};
#pragma unroll
      for (int j=0;j<8;++j) {
        acc[0][j] = fmaf(a0, wj[j], acc[0][j]);
        acc[1][j] = fmaf(a1, wj[j], acc[1][j]);
        acc[2][j] = fmaf(a2, wj[j], acc[2][j]);
        acc[3][j] = fmaf(a3, wj[j], acc[3][j]);
      }
    }
    float scl[8], shf[8];
#pragma unroll
    for (int j=0;j<8;++j) {
      int o = p*64 + 8*h + j;
      float r = g3[o] * rsqrtf(v3[o] + 1e-5f);
      scl[j] = r;
      shf[j] = (b3[o] - m3[o]) * r + bt3[o];
    }
    float vm[8];
#pragma unroll
    for (int j=0;j<8;++j) {
      float q0 = fmaxf(fmaf(acc[0][j], scl[j], shf[j]), 0.f);
      float q1 = fmaxf(fmaf(acc[1][j], scl[j], shf[j]), 0.f);
      float q2 = fmaxf(fmaf(acc[2][j], scl[j], shf[j]), 0.f);
      float q3 = fmaxf(fmaf(acc[3][j], scl[j], shf[j]), 0.f);
      vm[j] = fmaxf(fmaxf(q0,q1), fmaxf(q2,q3));
    }
#pragma unroll
    for (int mk = 8; mk < 64; mk <<= 1) {
#pragma unroll
      for (int j=0;j<8;++j) vm[j] = fmaxf(vm[j], __shfl_xor(vm[j], mk));
    }
    if (g == 0) {
      float* dst = out_feats + (size_t)bid*128 + p*64 + 8*h;
      *(float4*)dst       = make_float4(vm[0],vm[1],vm[2],vm[3]);
      *(float4*)(dst + 4) = make_float4(vm[4],vm[5],vm[6],vm[7]);
    }
  }
}

// ---------------------------------------------------------------------------
extern "C" void kernel_launch(void* const* d_in, const int* in_sizes, int n_in,
                              void* d_out, int out_size, void* d_ws, size_t ws_size,
                              hipStream_t stream) {
  const float* xyzs  = (const float*)d_in[0];
  const float* feats = (const float*)d_in[1];
  const float* w1  = (const float*)d_in[2];
  const float* b1  = (const float*)d_in[3];
  const float* g1  = (const float*)d_in[4];
  const float* bt1 = (const float*)d_in[5];
  const float* m1  = (const float*)d_in[6];
  const float* v1  = (const float*)d_in[7];
  const float* w2  = (const float*)d_in[8];
  const float* b2  = (const float*)d_in[9];
  const float* g2  = (const float*)d_in[10];
  const float* bt2 = (const float*)d_in[11];
  const float* m2  = (const float*)d_in[12];
  const float* v2  = (const float*)d_in[13];
  const float* w3  = (const float*)d_in[14];
  const float* b3  = (const float*)d_in[15];
  const float* g3  = (const float*)d_in[16];
  const float* bt3 = (const float*)d_in[17];
  const float* m3  = (const float*)d_in[18];
  const float* v3  = (const float*)d_in[19];

  float* out       = (float*)d_out;
  float* centers   = out;                          // [8][2048][3]
  float* out_feats = out + (size_t)NB * SCTR * 3;  // [8][2048][128]
  float* wT        = (float*)d_ws;                 // 16576 floats

  // blocks 0..7: FPS; blocks 8..24: weight transpose (17 blocks for 16576 elems)
  hipLaunchKernelGGL(fps_transpose_kernel, dim3(NB + 17), dim3(1024), 0, stream,
                     xyzs, w1, w2, w3, centers, wT);
  hipLaunchKernelGGL(sa_fused_kernel, dim3(NB * SCTR), dim3(64), 0, stream,
                     xyzs, feats, centers, wT,
                     b1, g1, bt1, m1, v1,
                     b2, g2, bt2, m2, v2,
                     b3, g3, bt3, m3, v3,
                     out_feats);
}